// Round 9
// baseline (4310.289 us; speedup 1.0000x reference)
//
#include <hip/hip_runtime.h>

#define BATCH 8
#define KSPLIT 8                       // blocks (CUs) per batch
#define NBLK (BATCH * KSPLIT)          // 64 blocks, all co-resident
#define N 32768
#define NPOINT 2048
#define NT 256                         // threads per block (4 waves)
#define NW (NT / 64)                   // 4 waves
#define QB (N / 2 / KSPLIT)            // f2 elems per block = 2048

typedef __attribute__((ext_vector_type(2))) float f2;

// Multi-CU FPS, round-8: r7's proven protocol, compute leg halved.
// KSPLIT=8, NT=256 -> 4 waves/block = 1 wave/SIMD (UPD issue 640->320 cyc),
// barrier fan-in 4.  All 8 blocks of batch b on XCD b (blk = k*8 + b).
// Per iteration:
//   1. UPD + per-lane u64 key (dist_bits<<32 | N-idx) + 6-step wave reduce
//   2. wave leaders: LDS atomicMax into s_key[j]  (per-iter slot, no reset)
//   3. one __syncthreads
//   4. t0: ONE relaxed agent-scope STORE of the block key to gslot[b][j][k]
//      (self-contained flag, always nonzero; no RMW, no fence, no counter)
//   5. every wave: lanes 0..7 poll the 8 block slots (plain atomic loads,
//      one 64B line), 3-step shfl max reduce, lane-0 broadcast -> sel
// Max dist + lowest original index on ties (dist >= 0 -> bits monotone).
// Bit-exact numpy semantics: contract off, (xx+yy)+zz order, no FMA.

#define REP8(M)  M(0) M(1) M(2) M(3) M(4) M(5) M(6) M(7)
#define REP8R(M) M(7) M(6) M(5) M(4) M(3) M(2) M(1) M(0)

__global__ __attribute__((amdgpu_flat_work_group_size(NT, NT),
                          amdgpu_waves_per_eu(2, 2)))
void fps_kernel(const float* __restrict__ pts_t,        // (B,3,N)
                float* __restrict__ out,                // (B,3,NPOINT)
                unsigned long long* __restrict__ gslot) // [B][NPOINT][KSPLIT]
{
#pragma clang fp contract(off)
    __shared__ unsigned long long s_key[NPOINT];   // 16 KiB, one slot/iter

    const int blk = blockIdx.x;
    const int b = blk & (BATCH - 1);          // batch -> XCD (round-robin)
    const int k = blk >> 3;                   // sub-block within batch
    const int t = threadIdx.x;
    const int l = t & 63;                     // lane id

    const float* __restrict__ px = pts_t + (size_t)b * 3 * N;
    const float* __restrict__ py = px + N;
    const float* __restrict__ pz = py + N;
    const f2* __restrict__ px2 = (const f2*)px;
    const f2* __restrict__ py2 = (const f2*)py;
    const f2* __restrict__ pz2 = (const f2*)pz;
    float* outx = out + (size_t)b * 3 * NPOINT;
    float* outy = outx + NPOINT;
    float* outz = outy + NPOINT;

    unsigned long long* __restrict__ slotb =
        gslot + (size_t)b * NPOINT * KSPLIT;

    // ---- all point state in registers: 8 f2 per array (16 pts/thread) ----
#define DECL(g) f2 x##g, y##g, z##g, T##g;
    REP8(DECL)
#undef DECL

#define LOADG(g) { const int q = k * QB + (g) * NT + t;           \
                   x##g = px2[q]; y##g = py2[q]; z##g = pz2[q];   \
                   T##g = (f2){1e10f, 1e10f}; }
    REP8(LOADG)
#undef LOADG

    // zero per-iteration LDS key slots (once)
    for (int i = t; i < NPOINT; i += NT) s_key[i] = 0ull;

    // First selected index is 0 (reference: idx[0] = 0).
    float lx = px[0], ly = py[0], lz = pz[0];
    if (k == 0 && t == 0) { outx[0] = lx; outy[0] = ly; outz[0] = lz; }
    __syncthreads();

    for (int j = 1; j < NPOINT; ++j) {
        const f2 lx2 = (f2){lx, lx};
        const f2 ly2 = (f2){ly, ly};
        const f2 lz2 = (f2){lz, lz};

        // --- update temps vs pivot; per-lane running max (pure VALU) ---
        f2 mx = (f2){0.0f, 0.0f};
#define UPD(g) { f2 dz = z##g - lz2;                                     \
                 f2 dx = x##g - lx2;                                     \
                 f2 dy = y##g - ly2;                                     \
                 f2 s  = (dx * dx + dy * dy) + dz * dz; /* numpy order */\
                 T##g.x = fminf(T##g.x, s.x);                            \
                 T##g.y = fminf(T##g.y, s.y);                            \
                 mx.x = fmaxf(mx.x, T##g.x);                             \
                 mx.y = fmaxf(mx.y, T##g.y); }
        REP8(UPD)
#undef UPD
        const float vlane = fmaxf(mx.x, mx.y);   // lane-local max

        // --- lane-local argmax (lowest original idx achieving vlane) ---
        int cand = N;
#define SCANG(g) { const int q = k * QB + (g) * NT + t;           \
                   cand = (T##g.y == vlane) ? 2 * q + 1 : cand;   \
                   cand = (T##g.x == vlane) ? 2 * q     : cand; }
        REP8R(SCANG)                       // descending -> lowest idx wins
#undef SCANG

        // --- per-lane key, wave max-reduce (lexicographic: dist, -idx) ---
        unsigned long long key =
            ((unsigned long long)__float_as_uint(vlane) << 32) |
            (unsigned)(N - cand);
#pragma unroll
        for (int off = 32; off >= 1; off >>= 1) {
            const unsigned long long o = __shfl_xor(key, off);
            key = o > key ? o : key;
        }

        // --- intra-block combine: one LDS atomic per wave, one barrier ---
        if (l == 0) atomicMax(&s_key[j], key);
        __syncthreads();

        // --- publish block key: ONE fire-and-forget store (t0 only) ---
        unsigned long long* __restrict__ slots = slotb + (size_t)j * KSPLIT;
        if (t == 0)
            __hip_atomic_store(&slots[k], s_key[j], __ATOMIC_RELAXED,
                               __HIP_MEMORY_SCOPE_AGENT);

        // --- every wave polls the 8 block slots (lanes 0..7, one 64B line) ---
        unsigned long long o = 0ull;
        if (l < KSPLIT) {
            do {
                o = __hip_atomic_load(&slots[l], __ATOMIC_RELAXED,
                                      __HIP_MEMORY_SCOPE_AGENT);
            } while (o == 0ull);
        }
#pragma unroll
        for (int off = 4; off >= 1; off >>= 1) {   // reduce lanes 0..7
            const unsigned long long s = __shfl_xor(o, off);
            o = s > o ? s : o;
        }
        const unsigned long long K = __shfl(o, 0); // broadcast to 64 lanes

        const int sel =
            __builtin_amdgcn_readfirstlane(N - (int)(unsigned)(K & 0xffffffffu));
        lx = px[sel];                      // uniform -> scalar load (L2-hit)
        ly = py[sel];
        lz = pz[sel];
        if (k == 0 && t == 0) { outx[j] = lx; outy[j] = ly; outz[j] = lz; }
    }
}

extern "C" void kernel_launch(void* const* d_in, const int* in_sizes, int n_in,
                              void* d_out, int out_size, void* d_ws, size_t ws_size,
                              hipStream_t stream) {
    // d_in[0]: points_xyz (B,N,3) — unused
    // d_in[1]: points_xyz_t (B,3,N)
    // d_in[2]: features_with_xyz (B,67,N) — unused
    // d_ws: gslot u64[B][NPOINT][KSPLIT] = 1 MiB, zeroed per launch
    const float* pts_t = (const float*)d_in[1];
    float* out = (float*)d_out;
    unsigned long long* gslot = (unsigned long long*)d_ws;
    hipMemsetAsync(d_ws, 0,
                   (size_t)BATCH * NPOINT * KSPLIT * sizeof(unsigned long long),
                   stream);
    fps_kernel<<<NBLK, NT, 0, stream>>>(pts_t, out, gslot);
}

// Round 10
// 3018.260 us; speedup vs baseline: 1.4281x; 1.4281x over previous
//
#include <hip/hip_runtime.h>

#define BATCH 8
#define KSPLIT 4                       // blocks (CUs) per batch (r7-proven)
#define NBLK (BATCH * KSPLIT)          // 32 blocks, all co-resident
#define N 32768
#define NPOINT 2048
#define NT 512                         // threads per block (8 waves)
#define QB (N / 2 / KSPLIT)            // f2 elems per block = 4096

typedef __attribute__((ext_vector_type(2))) float f2;

// Multi-CU FPS, round-9: r7 topology, tail rebuilt.
//  - wave reduce: DPP chain (row_shr 1/2/4/8 + row_bcast 15/31, 0-fill) on
//    UNSIGNED bits (all values >= 0 so IEEE order == uint order, 0 is the
//    max-identity) -> ~100 cyc VALU, no ds_bpermute.
//  - only WAVE 0 publishes + polls the 4 block slots (lanes 0..3, plain
//    agent-scope atomic loads); result broadcast via LDS + barrier 2.
//    Device-wide pollers: 256 waves -> 32. Publish store uncontended.
// Key = (dist_bits<<32 | N-idx): max dist, lowest original index on ties.
// Bit-exact numpy semantics: contract off, (xx+yy)+zz order, no FMA.

#define REP8(M)  M(0) M(1) M(2) M(3) M(4) M(5) M(6) M(7)
#define REP8R(M) M(7) M(6) M(5) M(4) M(3) M(2) M(1) M(0)

// one DPP max step: v = max(v, dpp_shift(v)), invalid lanes contribute 0
#define DPP_UMAX(v, ctrl) {                                                  \
    unsigned _t = (unsigned)__builtin_amdgcn_update_dpp(                     \
        0, (int)(v), (ctrl), 0xf, 0xf, true);                                \
    (v) = (v) > _t ? (v) : _t; }

// full wave-64 max of nonneg uint, result uniform via readlane 63
__device__ __forceinline__ unsigned wave_umax(unsigned v) {
    DPP_UMAX(v, 0x111);   // row_shr:1
    DPP_UMAX(v, 0x112);   // row_shr:2
    DPP_UMAX(v, 0x114);   // row_shr:4
    DPP_UMAX(v, 0x118);   // row_shr:8
    DPP_UMAX(v, 0x142);   // row_bcast:15
    DPP_UMAX(v, 0x143);   // row_bcast:31
    return (unsigned)__builtin_amdgcn_readlane((int)v, 63);
}

// u64 max with quad_perm exchange (lanes 0..3), ctrl compile-time const
#define QP_U64MAX(v, ctrl) {                                                 \
    unsigned _lo = (unsigned)__builtin_amdgcn_update_dpp(                    \
        0, (int)(unsigned)(v), (ctrl), 0xf, 0xf, false);                     \
    unsigned _hi = (unsigned)__builtin_amdgcn_update_dpp(                    \
        0, (int)(unsigned)((v) >> 32), (ctrl), 0xf, 0xf, false);             \
    unsigned long long _p = ((unsigned long long)_hi << 32) | _lo;           \
    (v) = _p > (v) ? _p : (v); }

__global__ __attribute__((amdgpu_flat_work_group_size(NT, NT),
                          amdgpu_waves_per_eu(2, 2)))
void fps_kernel(const float* __restrict__ pts_t,        // (B,3,N)
                float* __restrict__ out,                // (B,3,NPOINT)
                unsigned long long* __restrict__ gslot) // [B][NPOINT][KSPLIT]
{
#pragma clang fp contract(off)
    __shared__ unsigned long long s_key[NPOINT];   // 16 KiB, one slot/iter
    __shared__ unsigned long long s_res[2];        // winner key, dbuf

    const int blk = blockIdx.x;
    const int b = blk & (BATCH - 1);          // batch -> XCD (round-robin)
    const int k = blk >> 3;                   // sub-block within batch
    const int t = threadIdx.x;
    const int w = t >> 6;                     // wave id
    const int l = t & 63;                     // lane id

    const float* __restrict__ px = pts_t + (size_t)b * 3 * N;
    const float* __restrict__ py = px + N;
    const float* __restrict__ pz = py + N;
    const f2* __restrict__ px2 = (const f2*)px;
    const f2* __restrict__ py2 = (const f2*)py;
    const f2* __restrict__ pz2 = (const f2*)pz;
    float* outx = out + (size_t)b * 3 * NPOINT;
    float* outy = outx + NPOINT;
    float* outz = outy + NPOINT;

    unsigned long long* __restrict__ slotb =
        gslot + (size_t)b * NPOINT * KSPLIT;

    // ---- all point state in registers: 8 f2 per array (16 pts/thread) ----
#define DECL(g) f2 x##g, y##g, z##g, T##g;
    REP8(DECL)
#undef DECL

#define LOADG(g) { const int q = k * QB + (g) * NT + t;           \
                   x##g = px2[q]; y##g = py2[q]; z##g = pz2[q];   \
                   T##g = (f2){1e10f, 1e10f}; }
    REP8(LOADG)
#undef LOADG

    // zero per-iteration LDS key slots (once)
    for (int i = t; i < NPOINT; i += NT) s_key[i] = 0ull;

    // First selected index is 0 (reference: idx[0] = 0).
    float lx = px[0], ly = py[0], lz = pz[0];
    if (k == 0 && t == 0) { outx[0] = lx; outy[0] = ly; outz[0] = lz; }
    __syncthreads();

    for (int j = 1; j < NPOINT; ++j) {
        const f2 lx2 = (f2){lx, lx};
        const f2 ly2 = (f2){ly, ly};
        const f2 lz2 = (f2){lz, lz};

        // --- update temps vs pivot; per-lane running max (pure VALU) ---
        f2 mx = (f2){0.0f, 0.0f};
#define UPD(g) { f2 dz = z##g - lz2;                                     \
                 f2 dx = x##g - lx2;                                     \
                 f2 dy = y##g - ly2;                                     \
                 f2 s  = (dx * dx + dy * dy) + dz * dz; /* numpy order */\
                 T##g.x = fminf(T##g.x, s.x);                            \
                 T##g.y = fminf(T##g.y, s.y);                            \
                 mx.x = fmaxf(mx.x, T##g.x);                             \
                 mx.y = fmaxf(mx.y, T##g.y); }
        REP8(UPD)
#undef UPD
        const float vlane = fmaxf(mx.x, mx.y);   // lane-local max (>= 0)

        // --- lane-local argmax (lowest original idx achieving vlane) ---
        int cand = N;
#define SCANG(g) { const int q = k * QB + (g) * NT + t;           \
                   cand = (T##g.y == vlane) ? 2 * q + 1 : cand;   \
                   cand = (T##g.x == vlane) ? 2 * q     : cand; }
        REP8R(SCANG)                       // descending -> lowest idx wins
#undef SCANG

        // --- wave max via DPP (uint domain; values >= 0) ---
        const unsigned vbits = __float_as_uint(vlane);
        const unsigned Mbits = wave_umax(vbits);
        // tie-break: max of (N - cand) over lanes matching Mbits (>=1 exists)
        const unsigned uidx  = wave_umax(vbits == Mbits ? (unsigned)(N - cand)
                                                        : 0u);
        const unsigned long long key =
            ((unsigned long long)Mbits << 32) | uidx;

        // --- intra-block combine: one LDS atomic per wave, barrier 1 ---
        if (l == 0) atomicMax(&s_key[j], key);
        __syncthreads();                       // barrier 1

        // --- wave 0 only: publish block key, poll 4 slots, reduce ---
        unsigned long long* __restrict__ slots = slotb + (size_t)j * KSPLIT;
        if (w == 0) {
            if (l == 0)
                __hip_atomic_store(&slots[k], s_key[j], __ATOMIC_RELAXED,
                                   __HIP_MEMORY_SCOPE_AGENT);
            unsigned long long o = 0ull;
            if (l < KSPLIT) {
                do {
                    o = __hip_atomic_load(&slots[l], __ATOMIC_RELAXED,
                                          __HIP_MEMORY_SCOPE_AGENT);
                } while (o == 0ull);
            }
            QP_U64MAX(o, 0xB1);   // quad_perm [1,0,3,2]: xor 1
            QP_U64MAX(o, 0x4E);   // quad_perm [2,3,0,1]: xor 2
            if (l == 0) s_res[j & 1] = o;      // lane 0 of quad 0 has max
        }
        __syncthreads();                       // barrier 2

        const unsigned long long K = s_res[j & 1];
        const int sel =
            __builtin_amdgcn_readfirstlane(N - (int)(unsigned)(K & 0xffffffffu));
        lx = px[sel];                      // uniform -> scalar load (L2-hit)
        ly = py[sel];
        lz = pz[sel];
        if (k == 0 && t == 0) { outx[j] = lx; outy[j] = ly; outz[j] = lz; }
    }
}

extern "C" void kernel_launch(void* const* d_in, const int* in_sizes, int n_in,
                              void* d_out, int out_size, void* d_ws, size_t ws_size,
                              hipStream_t stream) {
    // d_in[0]: points_xyz (B,N,3) — unused
    // d_in[1]: points_xyz_t (B,3,N)
    // d_in[2]: features_with_xyz (B,67,N) — unused
    // d_ws: gslot u64[B][NPOINT][KSPLIT] = 512 KiB, zeroed per launch
    const float* pts_t = (const float*)d_in[1];
    float* out = (float*)d_out;
    unsigned long long* gslot = (unsigned long long*)d_ws;
    hipMemsetAsync(d_ws, 0,
                   (size_t)BATCH * NPOINT * KSPLIT * sizeof(unsigned long long),
                   stream);
    fps_kernel<<<NBLK, NT, 0, stream>>>(pts_t, out, gslot);
}

// Round 11
// 2722.991 us; speedup vs baseline: 1.5829x; 1.1084x over previous
//
#include <hip/hip_runtime.h>

#define BATCH 8
#define KSPLIT 8                       // blocks (CUs) per batch
#define NBLK (BATCH * KSPLIT)          // 64 blocks, 1 per CU, all co-resident
#define N 32768
#define NPOINT 2048
#define NT 256                         // threads per block (4 waves = 1/SIMD)
#define QB (N / 2 / KSPLIT)            // f2 elems per block = 2048

typedef __attribute__((ext_vector_type(2))) float f2;

// Multi-CU FPS, round-10: r9's tail protocol at KSPLIT=8.
// NT=256 -> 1 wave/SIMD: UPD issue 640->320 cyc, DPP chains uncontended.
// Per iteration:
//   1. UPD + lane argmax + DPP wave reduce (uint domain, 0-identity)
//   2. wave leaders: LDS atomicMax into s_key[j]; barrier 1
//   3. wave 0: ONE relaxed agent-scope store of block key to gslot[b][j][k];
//      lanes 0..7 poll the 8 slots (one 64B line, plain atomic loads);
//      quad_perm DPP reduce + 2 readlanes + uniform compare -> winner key
//   4. barrier 2; broadcast via LDS; uniform scalar pivot fetch
// Key = (dist_bits<<32 | N-idx): max dist, lowest original index on ties
// (dist >= 0 so float bits are monotone; N-idx >= 1 so key != 0).
// Bit-exact numpy semantics: contract off, (xx+yy)+zz order, no FMA.

#define REP8(M)  M(0) M(1) M(2) M(3) M(4) M(5) M(6) M(7)
#define REP8R(M) M(7) M(6) M(5) M(4) M(3) M(2) M(1) M(0)

// one DPP max step: v = max(v, dpp_shift(v)), invalid lanes contribute 0
#define DPP_UMAX(v, ctrl) {                                                  \
    unsigned _t = (unsigned)__builtin_amdgcn_update_dpp(                     \
        0, (int)(v), (ctrl), 0xf, 0xf, true);                                \
    (v) = (v) > _t ? (v) : _t; }

// full wave-64 max of nonneg uint, result uniform via readlane 63
__device__ __forceinline__ unsigned wave_umax(unsigned v) {
    DPP_UMAX(v, 0x111);   // row_shr:1
    DPP_UMAX(v, 0x112);   // row_shr:2
    DPP_UMAX(v, 0x114);   // row_shr:4
    DPP_UMAX(v, 0x118);   // row_shr:8
    DPP_UMAX(v, 0x142);   // row_bcast:15
    DPP_UMAX(v, 0x143);   // row_bcast:31
    return (unsigned)__builtin_amdgcn_readlane((int)v, 63);
}

// u64 max with quad_perm exchange, ctrl compile-time const
#define QP_U64MAX(v, ctrl) {                                                 \
    unsigned _lo = (unsigned)__builtin_amdgcn_update_dpp(                    \
        0, (int)(unsigned)(v), (ctrl), 0xf, 0xf, false);                     \
    unsigned _hi = (unsigned)__builtin_amdgcn_update_dpp(                    \
        0, (int)(unsigned)((v) >> 32), (ctrl), 0xf, 0xf, false);             \
    unsigned long long _p = ((unsigned long long)_hi << 32) | _lo;           \
    (v) = _p > (v) ? _p : (v); }

__device__ __forceinline__ unsigned long long rdlane_u64(unsigned long long v,
                                                         int lane) {
    const unsigned lo = (unsigned)__builtin_amdgcn_readlane(
        (int)(unsigned)v, lane);
    const unsigned hi = (unsigned)__builtin_amdgcn_readlane(
        (int)(unsigned)(v >> 32), lane);
    return ((unsigned long long)hi << 32) | lo;
}

__global__ __attribute__((amdgpu_flat_work_group_size(NT, NT),
                          amdgpu_waves_per_eu(2, 2)))
void fps_kernel(const float* __restrict__ pts_t,        // (B,3,N)
                float* __restrict__ out,                // (B,3,NPOINT)
                unsigned long long* __restrict__ gslot) // [B][NPOINT][KSPLIT]
{
#pragma clang fp contract(off)
    __shared__ unsigned long long s_key[NPOINT];   // 16 KiB, one slot/iter
    __shared__ unsigned long long s_res[2];        // winner key, dbuf

    const int blk = blockIdx.x;
    const int b = blk & (BATCH - 1);          // batch -> XCD (round-robin)
    const int k = blk >> 3;                   // sub-block within batch
    const int t = threadIdx.x;
    const int w = t >> 6;                     // wave id
    const int l = t & 63;                     // lane id

    const float* __restrict__ px = pts_t + (size_t)b * 3 * N;
    const float* __restrict__ py = px + N;
    const float* __restrict__ pz = py + N;
    const f2* __restrict__ px2 = (const f2*)px;
    const f2* __restrict__ py2 = (const f2*)py;
    const f2* __restrict__ pz2 = (const f2*)pz;
    float* outx = out + (size_t)b * 3 * NPOINT;
    float* outy = outx + NPOINT;
    float* outz = outy + NPOINT;

    unsigned long long* __restrict__ slotb =
        gslot + (size_t)b * NPOINT * KSPLIT;

    // ---- all point state in registers: 8 f2 per array (16 pts/thread) ----
#define DECL(g) f2 x##g, y##g, z##g, T##g;
    REP8(DECL)
#undef DECL

#define LOADG(g) { const int q = k * QB + (g) * NT + t;           \
                   x##g = px2[q]; y##g = py2[q]; z##g = pz2[q];   \
                   T##g = (f2){1e10f, 1e10f}; }
    REP8(LOADG)
#undef LOADG

    // zero per-iteration LDS key slots (once)
    for (int i = t; i < NPOINT; i += NT) s_key[i] = 0ull;

    // First selected index is 0 (reference: idx[0] = 0).
    float lx = px[0], ly = py[0], lz = pz[0];
    if (k == 0 && t == 0) { outx[0] = lx; outy[0] = ly; outz[0] = lz; }
    __syncthreads();

    for (int j = 1; j < NPOINT; ++j) {
        const f2 lx2 = (f2){lx, lx};
        const f2 ly2 = (f2){ly, ly};
        const f2 lz2 = (f2){lz, lz};

        // --- update temps vs pivot; per-lane running max (pure VALU) ---
        f2 mx = (f2){0.0f, 0.0f};
#define UPD(g) { f2 dz = z##g - lz2;                                     \
                 f2 dx = x##g - lx2;                                     \
                 f2 dy = y##g - ly2;                                     \
                 f2 s  = (dx * dx + dy * dy) + dz * dz; /* numpy order */\
                 T##g.x = fminf(T##g.x, s.x);                            \
                 T##g.y = fminf(T##g.y, s.y);                            \
                 mx.x = fmaxf(mx.x, T##g.x);                             \
                 mx.y = fmaxf(mx.y, T##g.y); }
        REP8(UPD)
#undef UPD
        const float vlane = fmaxf(mx.x, mx.y);   // lane-local max (>= 0)

        // --- lane-local argmax (lowest original idx achieving vlane) ---
        int cand = N;
#define SCANG(g) { const int q = k * QB + (g) * NT + t;           \
                   cand = (T##g.y == vlane) ? 2 * q + 1 : cand;   \
                   cand = (T##g.x == vlane) ? 2 * q     : cand; }
        REP8R(SCANG)                       // descending -> lowest idx wins
#undef SCANG

        // --- wave max via DPP (uint domain; values >= 0) ---
        const unsigned vbits = __float_as_uint(vlane);
        const unsigned Mbits = wave_umax(vbits);
        // tie-break: max of (N - cand) over lanes matching Mbits (>=1 exists)
        const unsigned uidx  = wave_umax(vbits == Mbits ? (unsigned)(N - cand)
                                                        : 0u);
        const unsigned long long key =
            ((unsigned long long)Mbits << 32) | uidx;

        // --- intra-block combine: one LDS atomic per wave, barrier 1 ---
        if (l == 0) atomicMax(&s_key[j], key);
        __syncthreads();                       // barrier 1

        // --- wave 0 only: publish block key, poll 8 slots, reduce ---
        unsigned long long* __restrict__ slots = slotb + (size_t)j * KSPLIT;
        if (w == 0) {
            if (l == 0)
                __hip_atomic_store(&slots[k], s_key[j], __ATOMIC_RELAXED,
                                   __HIP_MEMORY_SCOPE_AGENT);
            unsigned long long o = 0ull;
            if (l < KSPLIT) {                  // lanes 0..7, one 64B line
                do {
                    o = __hip_atomic_load(&slots[l], __ATOMIC_RELAXED,
                                          __HIP_MEMORY_SCOPE_AGENT);
                } while (o == 0ull);
            }
            QP_U64MAX(o, 0xB1);   // quad_perm [1,0,3,2]: xor 1
            QP_U64MAX(o, 0x4E);   // quad_perm [2,3,0,1]: xor 2
            // quad 0 holds max(slots 0..3), quad 1 holds max(slots 4..7)
            const unsigned long long m03 = rdlane_u64(o, 0);
            const unsigned long long m47 = rdlane_u64(o, 4);
            const unsigned long long K = m47 > m03 ? m47 : m03;  // uniform
            if (l == 0) s_res[j & 1] = K;
        }
        __syncthreads();                       // barrier 2

        const unsigned long long K = s_res[j & 1];
        const int sel =
            __builtin_amdgcn_readfirstlane(N - (int)(unsigned)(K & 0xffffffffu));
        lx = px[sel];                      // uniform -> scalar load (L2-hit)
        ly = py[sel];
        lz = pz[sel];
        if (k == 0 && t == 0) { outx[j] = lx; outy[j] = ly; outz[j] = lz; }
    }
}

extern "C" void kernel_launch(void* const* d_in, const int* in_sizes, int n_in,
                              void* d_out, int out_size, void* d_ws, size_t ws_size,
                              hipStream_t stream) {
    // d_in[0]: points_xyz (B,N,3) — unused
    // d_in[1]: points_xyz_t (B,3,N)
    // d_in[2]: features_with_xyz (B,67,N) — unused
    // d_ws: gslot u64[B][NPOINT][KSPLIT] = 1 MiB, zeroed per launch
    const float* pts_t = (const float*)d_in[1];
    float* out = (float*)d_out;
    unsigned long long* gslot = (unsigned long long*)d_ws;
    hipMemsetAsync(d_ws, 0,
                   (size_t)BATCH * NPOINT * KSPLIT * sizeof(unsigned long long),
                   stream);
    fps_kernel<<<NBLK, NT, 0, stream>>>(pts_t, out, gslot);
}